// Round 13
// baseline (58150.684 us; speedup 1.0000x reference)
//
#include <hip/hip_runtime.h>

typedef __attribute__((ext_vector_type(4))) float f32x4;
typedef __attribute__((ext_vector_type(8))) short bf16x8;
typedef __attribute__((ext_vector_type(4))) short bf16x4;
typedef __attribute__((ext_vector_type(4))) int i4v;
typedef _Float16 f16;
typedef __attribute__((ext_vector_type(8))) _Float16 f16x8;
typedef __attribute__((ext_vector_type(4))) _Float16 f16x4;

#define DEV static __device__ __forceinline__

constexpr int NB = 128;
constexpr int NS = 256;
constexpr int NT = 256;
constexpr int NV = 512;
constexpr int NH = 512;
constexpr int BH = NB * NH;  // 65536
constexpr float NEGV = -1e9f;

DEV float bf2f(short u) {
  unsigned int i = ((unsigned int)(unsigned short)u) << 16;
  float f; __builtin_memcpy(&f, &i, 4); return f;
}
DEV short f2bf(float x) {
  unsigned int i; __builtin_memcpy(&i, &x, 4);
  i += 0x7fffu + ((i >> 16) & 1u);
  return (short)(i >> 16);
}
DEV int pk(float x) {
  short h = f2bf(x);
  short l = f2bf(x - bf2f(h));
  return ((int)(unsigned short)h << 16) | (int)(unsigned short)l;
}
DEV float upkf(int v) { return bf2f((short)(v >> 16)) + bf2f((short)(v & 0xffff)); }
DEV float sigm(float x) { return 1.0f / (1.0f + __expf(-x)); }
DEV float tanh_(float x) { return 1.0f - 2.0f / (__expf(2.0f * x) + 1.0f); }
DEV f32x4 mfma16(bf16x8 a, bf16x8 b, f32x4 c) {
  return __builtin_amdgcn_mfma_f32_16x16x32_bf16(a, b, c, 0, 0, 0);
}

// ---- agent-scope (L3-coherent) atomics for intra-kernel cross-WG data ----
DEV int aload_i(const int* p) { return __hip_atomic_load(p, __ATOMIC_RELAXED, __HIP_MEMORY_SCOPE_AGENT); }
DEV void astore_i(int* p, int v) { __hip_atomic_store(p, v, __ATOMIC_RELAXED, __HIP_MEMORY_SCOPE_AGENT); }
DEV unsigned long long aload_l(const unsigned long long* p) {
  return __hip_atomic_load(p, __ATOMIC_RELAXED, __HIP_MEMORY_SCOPE_AGENT);
}
DEV float aload_f(const float* p) { return __hip_atomic_load(p, __ATOMIC_RELAXED, __HIP_MEMORY_SCOPE_AGENT); }
DEV void astore_f(float* p, float v) { __hip_atomic_store(p, v, __ATOMIC_RELAXED, __HIP_MEMORY_SCOPE_AGENT); }

// tree grid-barrier: 8 sub-counters (64B apart) + top counter; monotonic, no reset
DEV void gbar(int* bars, int sub, int subsz, int nsub, int bc) {
  asm volatile("s_waitcnt vmcnt(0) lgkmcnt(0)" ::: "memory");
  __syncthreads();
  if (threadIdx.x == 0) {
    int a = __hip_atomic_fetch_add(&bars[sub * 16], 1, __ATOMIC_RELAXED, __HIP_MEMORY_SCOPE_AGENT);
    if (a + 1 == subsz * bc)
      __hip_atomic_fetch_add(&bars[128], 1, __ATOMIC_RELAXED, __HIP_MEMORY_SCOPE_AGENT);
    while (aload_i(&bars[128]) < nsub * bc) __builtin_amdgcn_s_sleep(4);
    asm volatile("" ::: "memory");
  }
  __syncthreads();
}

// ---- fragment builders (all produce bf16 hi/lo pairs) ----
DEV void frag_zero(bf16x8& ah, bf16x8& al) { bf16x8 z{}; ah = z; al = z; }
DEV void frag_f32(const float* p, bf16x8& ah, bf16x8& al) {
  f32x4 a = *(const f32x4*)p, b = *(const f32x4*)(p + 4);
#pragma unroll
  for (int j = 0; j < 4; ++j) {
    short h0 = f2bf(a[j]); ah[j] = h0; al[j] = f2bf(a[j] - bf2f(h0));
    short h1 = f2bf(b[j]); ah[4 + j] = h1; al[4 + j] = f2bf(b[j] - bf2f(h1));
  }
}
DEV void frag_f16(const f16* p, bf16x8& ah, bf16x8& al) {
  f16x8 v = *(const f16x8*)p;
#pragma unroll
  for (int j = 0; j < 8; ++j) {
    float f = (float)v[j];
    short h = f2bf(f); ah[j] = h; al[j] = f2bf(f - bf2f(h));
  }
}
DEV void frag_pka(const int* p, bf16x8& ah, bf16x8& al) {  // packed via agent loads
#pragma unroll
  for (int jj = 0; jj < 4; ++jj) {
    unsigned long long u = aload_l((const unsigned long long*)p + jj);
    int va = (int)u, vb = (int)(u >> 32);
    ah[jj * 2] = (short)(va >> 16); al[jj * 2] = (short)(va & 0xffff);
    ah[jj * 2 + 1] = (short)(vb >> 16); al[jj * 2 + 1] = (short)(vb & 0xffff);
  }
}
DEV void frag_pk(const int* p, bf16x8& ah, bf16x8& al) {  // packed, plain loads
  i4v a = *(const i4v*)p; i4v b = *(const i4v*)(p + 4);
#pragma unroll
  for (int j = 0; j < 4; ++j) {
    ah[j] = (short)(a[j] >> 16); al[j] = (short)(a[j] & 0xffff);
    ah[4 + j] = (short)(b[j] >> 16); al[4 + j] = (short)(b[j] & 0xffff);
  }
}
// ctx merge of 4 fp32 quarter-partials with 4 softmax scalars, then bf16-pair
DEV void frag_ctxq(const float* p0, const float* p1, const float* p2, const float* p3,
                   float w0, float w1, float w2, float w3, bf16x8& ah, bf16x8& al) {
#pragma unroll
  for (int jj = 0; jj < 4; ++jj) {
    unsigned long long u0 = aload_l((const unsigned long long*)p0 + jj);
    unsigned long long u1 = aload_l((const unsigned long long*)p1 + jj);
    unsigned long long u2 = aload_l((const unsigned long long*)p2 + jj);
    unsigned long long u3 = aload_l((const unsigned long long*)p3 + jj);
    float ma = w0 * __uint_as_float((unsigned)u0) + w1 * __uint_as_float((unsigned)u1) +
               w2 * __uint_as_float((unsigned)u2) + w3 * __uint_as_float((unsigned)u3);
    float mb = w0 * __uint_as_float((unsigned)(u0 >> 32)) + w1 * __uint_as_float((unsigned)(u1 >> 32)) +
               w2 * __uint_as_float((unsigned)(u2 >> 32)) + w3 * __uint_as_float((unsigned)(u3 >> 32));
    short ha = f2bf(ma); ah[jj * 2] = ha; al[jj * 2] = f2bf(ma - bf2f(ha));
    short hb = f2bf(mb); ah[jj * 2 + 1] = hb; al[jj * 2 + 1] = f2bf(mb - bf2f(hb));
  }
}

// ---- prep kernels ----
__global__ void k_init(float* hinit, int* bars) {
  int i = blockIdx.x * 256 + threadIdx.x;
  if (i < 4 * BH) hinit[i] = 0.f;
  if (i < 768) bars[i] = 0;
}
__global__ void k_bias(const float* bi0, const float* bh0, const float* bi1, const float* bh1,
                       const float* dbi0, const float* dbh0, const float* dbi1, const float* dbh1,
                       float* e0, float* e1, float* d0, float* d1) {
  int i = blockIdx.x * 256 + threadIdx.x;
  if (i < 4096) { e0[i] = bi0[i] + bh0[i]; e1[i] = bi1[i] + bh1[i]; }
  if (i < 2048) { d0[i] = dbi0[i] + dbh0[i]; d1[i] = dbi1[i] + dbh1[i]; }
}
// fp32 W [nmat][2048][K] -> fragment layout [q=((mat*32+ct)*4+g)*KS+ks][hi 512 | lo 512 shorts]
__global__ void k_fragW(const float* __restrict__ src, short* __restrict__ dst,
                        int K, long tot) {
  long id = (long)blockIdx.x * 256 + threadIdx.x;
  if (id >= tot) return;
  int l = (int)(id & 63);
  long q = id >> 6;
  int KS = K >> 5;
  int ks = (int)(q % KS);
  long q2 = q / KS;
  int g = (int)(q2 & 3);
  long q3 = q2 >> 2;
  long mat = q3 >> 5;
  int ct = (int)(q3 & 31);
  const float* s = src + (mat * 2048 + g * 512 + ct * 16 + (l & 15)) * (long)K +
                   ks * 32 + (l >> 4) * 8;
  short* d = dst + q * 1024 + l * 8;
#pragma unroll
  for (int j = 0; j < 8; ++j) {
    float x = s[j];
    short h = f2bf(x);
    d[j] = h;
    d[512 + j] = f2bf(x - bf2f(h));
  }
}
// Wq [1024][512] fp32 -> [n 512][k 1024] packed bf16-pair ints (transposed)
__global__ void k_convT(const float* __restrict__ src, int* __restrict__ dst) {
  int i = blockIdx.x * 256 + threadIdx.x;  // 524288
  int n = i >> 10, k = i & 1023;
  dst[i] = pk(src[k * 512 + n]);
}

// ---- encoder layer, LDS-pinned weights (round-11 form, proven) ----
template <int LAYER>
__global__ __launch_bounds__(512, 2) void k_enc(
    const int* __restrict__ source, const float* __restrict__ emb,
    const f16* __restrict__ y0in,
    const short* __restrict__ WihP, const short* __restrict__ WhhP,
    const float* __restrict__ bsum,
    int* __restrict__ hbuf, f16* __restrict__ yout,
    float* __restrict__ hinitL, float* __restrict__ pbufE, int* bars) {
  constexpr int EX = LAYER ? 1024 : 256;
  constexpr int XK = EX / 32;
  constexpr int TOT = XK + 16;
  constexpr int HALF = TOT / 2;
  __shared__ short sW[HALF * 1024];
  const int wg = blockIdx.x, tid = threadIdx.x, wv = tid >> 6, lane = tid & 63;
  const int l15 = lane & 15, klane = (lane >> 4) * 8;
  const int xx = wg & 7, ii = wg >> 3;
  const int ct = xx * 4 + (ii & 3), g = (ii >> 2) & 3, dir = (ii >> 4) & 1, kp = (ii >> 5) & 1;
  const int cb = ct * 16;
  const short* wih = WihP + (long)dir * 4096 * EX;
  const short* whh = WhhP + (long)dir * 4096 * 512;
  const float* bs = bsum + dir * 2048;
  for (int i = tid; i < HALF * 128; i += 512) {
    int uu = i >> 7, off = (i & 127) * 8;
    int u = kp * HALF + uu;
    const short* src = (u < XK)
        ? wih + ((long)((ct * 4 + g) * XK + u) << 10) + off
        : whh + ((long)((ct * 4 + g) * 16 + (u - XK)) << 10) + off;
    *(bf16x8*)(sW + uu * 1024 + off) = *(const bf16x8*)src;
  }
  int bc = 0;
  {
    int i = wg * 512 + tid;
    int dp = i >> 16, rr = (i >> 9) & 127, c2 = i & 511;
    astore_i(&hbuf[dp * BH + rr * NH + c2], 0);
  }
  gbar(bars, xx, 64, 8, ++bc);
  const int arow = wv * 16 + l15;
  const int frow = g * 32 + (tid >> 4), fcol = cb + (tid & 15);
  float creg = 0.f;
  for (int t = 0; t < NS; ++t) {
    const int tt = dir ? (NS - 1 - t) : t;
    {
      f32x4 acc = {0.f, 0.f, 0.f, 0.f};
      int tok = 0;
      const float* er = nullptr;
      if (LAYER == 0 && kp == 0) { tok = source[arow * NS + tt]; er = emb + (long)tok * 256; }
      const f16* xr = LAYER ? (y0in + ((long)tt * NB + arow) * 1024 + klane) : nullptr;
      const int* hr = hbuf + (long)(dir * 2 + (t & 1)) * BH + arow * NH + klane;
#pragma unroll
      for (int uu = 0; uu < HALF; ++uu) {
        int u = kp * HALF + uu;
        bf16x8 ah, al;
        if (u < XK) {
          if (LAYER == 0) { if (tok) frag_f32(er + u * 32 + klane, ah, al); else frag_zero(ah, al); }
          else frag_f16(xr + u * 32, ah, al);
        } else {
          frag_pka(hr + (u - XK) * 32, ah, al);
        }
        const short* w = sW + uu * 1024 + lane * 8;
        bf16x8 wh = *(const bf16x8*)w, wl = *(const bf16x8*)(w + 512);
        acc = mfma16(ah, wh, acc);
        acc = mfma16(al, wh, acc);
        acc = mfma16(ah, wl, acc);
      }
#pragma unroll
      for (int r = 0; r < 4; ++r) {
        int row = wv * 16 + ((lane >> 4) << 2) + r;
        astore_f(&pbufE[(((long)(kp * 2 + dir) * 128 + row) << 11) + g * 512 + cb + l15], acc[r]);
      }
    }
    gbar(bars, xx, 64, 8, ++bc);
    if (kp == 0) {
      float g4[4];
#pragma unroll
      for (int gp = 0; gp < 4; ++gp)
        g4[gp] = aload_f(&pbufE[(((long)dir * 128 + frow) << 11) + gp * 512 + fcol]) +
                 aload_f(&pbufE[(((long)(2 + dir) * 128 + frow) << 11) + gp * 512 + fcol]) +
                 bs[gp * 512 + fcol];
      float iv = sigm(g4[0]), fv = sigm(g4[1]), gv = tanh_(g4[2]), ov = sigm(g4[3]);
      float cv = fv * creg + iv * gv; creg = cv;
      float hv = ov * tanh_(cv);
      astore_i(&hbuf[(long)(dir * 2 + ((t + 1) & 1)) * BH + frow * NH + fcol], pk(hv));
      if (LAYER == 0) yout[((long)tt * NB + frow) * 1024 + dir * 512 + fcol] = (f16)hv;
      else           yout[((long)frow * NS + tt) * 1024 + dir * 512 + fcol] = (f16)hv;
      if (t == NS - 1) {
        atomicAdd(&hinitL[frow * NH + fcol], hv);
        atomicAdd(&hinitL[BH + frow * NH + fcol], cv);
      }
    }
    gbar(bars, xx, 64, 8, ++bc);
  }
}

// aprime = eo @ Wq : M=32768 N=512 K=1024
__global__ __launch_bounds__(256) void k_gemm_ap(const f16* __restrict__ A,
    const int* __restrict__ WPk, f16* __restrict__ C) {
  const int mt = blockIdx.x & 511, nt = blockIdx.x >> 9;
  const int wv = threadIdx.x >> 6, lane = threadIdx.x & 63;
  const int l15 = lane & 15, klane = (lane >> 4) * 8;
  const int r0 = mt * 64 + wv * 16, n0 = nt * 64;
  f32x4 acc[4] = {{0,0,0,0},{0,0,0,0},{0,0,0,0},{0,0,0,0}};
  const f16* ar = A + (long)(r0 + l15) * 1024 + klane;
  for (int k = 0; k < 1024; k += 32) {
    bf16x8 ah, al;
    frag_f16(ar + k, ah, al);
#pragma unroll
    for (int g = 0; g < 4; ++g) {
      bf16x8 wh, wl;
      frag_pk(WPk + (long)(n0 + g * 16 + l15) * 1024 + k + klane, wh, wl);
      acc[g] = mfma16(ah, wh, acc[g]);
      acc[g] = mfma16(al, wh, acc[g]);
      acc[g] = mfma16(ah, wl, acc[g]);
    }
  }
#pragma unroll
  for (int g = 0; g < 4; ++g)
#pragma unroll
    for (int r = 0; r < 4; ++r) {
      int m = r0 + ((lane >> 4) << 2) + r;
      C[(long)m * 512 + n0 + g * 16 + l15] = (f16)acc[g][r];
    }
}

__global__ void k_sbias(const f16* __restrict__ eo, const float* __restrict__ bq,
                        float* __restrict__ sb) {
  int row = blockIdx.x * 256 + threadIdx.x;
  const f16* p = eo + (long)row * 1024;
  float acc = 0.f;
  for (int k = 0; k < 1024; k += 8) {
    f16x8 v = *(const f16x8*)(p + k);
#pragma unroll
    for (int j = 0; j < 8; ++j) acc += (float)v[j] * bq[k + j];
  }
  sb[row] = acc;
}

// persistent decoder: 512 WGs x 512 thr, 3 barriers/step, launch_bounds (512,4)
// => VGPR<=128 => 2 WGs/CU => all 512 co-resident (required for the grid barrier).
// P2: attention per (b, s-quarter of 64). P4/P5: cells on WGs 0..63 (R8 form).
__global__ __launch_bounds__(512, 4) void k_dec(
    const int* __restrict__ dects, const float* __restrict__ emb,
    const int* __restrict__ source,
    const f16* __restrict__ aprime, const float* __restrict__ sbias,
    const f16* __restrict__ eo,
    const short* __restrict__ dW0ih, const short* __restrict__ dW0hh,
    const short* __restrict__ dW1ih, const short* __restrict__ dW1hh,
    const float* __restrict__ db0, const float* __restrict__ db1,
    const float* __restrict__ hinit,
    int* __restrict__ d0h, int* __restrict__ d1h,
    float* __restrict__ attscal, float* __restrict__ attvq,
    f16* __restrict__ d1a, int* bars) {
  __shared__ float s_d1[512];
  __shared__ float s_scp[512];
  __shared__ float s_w[64];
  __shared__ f32x4 s_cx[256];
  __shared__ f32x4 sC[4][4][64];
  const int wg = blockIdx.x, tid = threadIdx.x, wv = tid >> 6, lane = tid & 63;
  const int tw = wv & 3, grp = wv >> 2;
  const int l15 = lane & 15, klane = (lane >> 4) * 8;
  int bc = 0;
  if (wg < 256 && tid < 256) {  // init parity-0 states from encoder-summed finals
    int idx = wg * 256 + tid;
    astore_i(&d0h[idx], pk(hinit[idx]));
    astore_i(&d1h[idx], pk(hinit[2 * BH + idx]));
  }
  const bool cw = (wg < 64);
  int r0 = 0, cb = 0;
  f32x4 c0 = {0,0,0,0}, c1 = {0,0,0,0};
  if (cw) {
    int xx = wg & 7, ii = wg >> 3;
    cb = (xx * 4 + (ii & 3)) * 16;
    r0 = (ii >> 2) * 64 + tw * 16;
    if (grp == 0) {
#pragma unroll
      for (int r = 0; r < 4; ++r) {
        int row = r0 + ((lane >> 4) << 2) + r;
        c0[r] = hinit[BH + row * NH + cb + l15];
        c1[r] = hinit[3 * BH + row * NH + cb + l15];
      }
    }
  }
  gbar(bars, wg & 7, 64, 8, ++bc);
  const int b = wg >> 2, sq = wg & 3;
  const int arow = r0 + l15, col = cb + l15;
  for (int t = 0; t < NT; ++t) {
    const int cur = t & 1, nxt = cur ^ 1;
    // ---- P2: attention (quarter) ----
    {
      if (tid < 256) {
        unsigned long long u = aload_l((const unsigned long long*)(d1h + cur * BH + b * NH) + tid);
        s_d1[tid * 2] = upkf((int)u);
        s_d1[tid * 2 + 1] = upkf((int)(u >> 32));
      }
      __syncthreads();
      {  // scores: 8 K-chunks of 64 x 64 sl
        int kq = tid >> 6, sl = tid & 63;
        const f16* ap = aprime + (long)(b * NS + sq * 64 + sl) * 512 + kq * 64;
        const float* sd = s_d1 + kq * 64;
        float acc = 0.f;
#pragma unroll
        for (int k = 0; k < 64; k += 8) {
          f16x8 v = *(const f16x8*)(ap + k);
#pragma unroll
          for (int j = 0; j < 8; ++j) acc += (float)v[j] * sd[k + j];
        }
        s_scp[kq * 64 + sl] = acc;
      }
      __syncthreads();
      if (tid < 64) {
        int s = sq * 64 + tid;
        float sv = 0.f;
#pragma unroll
        for (int kq = 0; kq < 8; ++kq) sv += s_scp[kq * 64 + tid];
        sv = (source[b * NS + s] != 0) ? (sv + sbias[b * NS + s]) : NEGV;
        float m = sv;
#pragma unroll
        for (int o = 32; o > 0; o >>= 1) m = fmaxf(m, __shfl_xor(m, o, 64));
        float p = __expf(sv - m);
        s_w[tid] = p;
        float q = p;
#pragma unroll
        for (int o = 32; o > 0; o >>= 1) q += __shfl_xor(q, o, 64);
        if (lane == 0) {
          astore_f(&attscal[(b * 4 + sq) * 2 + 0], m);
          astore_f(&attscal[(b * 4 + sq) * 2 + 1], q);
        }
      }
      __syncthreads();
      {  // ctx partial: 2 s-halves of 32, LDS-combined -> one fp32 partial per quarter
        int hs = tid >> 8, dd = (tid & 255) * 4;
        f32x4 a = {0.f, 0.f, 0.f, 0.f};
        const f16* bp = eo + (long)(b * NS + sq * 64 + hs * 32) * 1024 + dd;
        const float* wp = s_w + hs * 32;
#pragma unroll 8
        for (int sl = 0; sl < 32; ++sl) {
          float w = wp[sl];
          f16x4 v = *(const f16x4*)(bp + (long)sl * 1024);
          a[0] += w * (float)v[0]; a[1] += w * (float)v[1];
          a[2] += w * (float)v[2]; a[3] += w * (float)v[3];
        }
        if (hs) s_cx[tid & 255] = a;
        __syncthreads();
        if (!hs) {
          f32x4 o = s_cx[tid];
          a[0] += o[0]; a[1] += o[1]; a[2] += o[2]; a[3] += o[3];
          float* op = attvq + (long)(b * 4 + sq) * 1024 + dd;
          astore_f(op + 0, a[0]); astore_f(op + 1, a[1]);
          astore_f(op + 2, a[2]); astore_f(op + 3, a[3]);
        }
      }
    }
    gbar(bars, wg & 7, 64, 8, ++bc);
    // ---- P4: cell0; A: emb(8)+ctx(0..19); B: ctx(20..31)+h(16); sC combine ----
    if (cw) {
      float mq0 = aload_f(&attscal[(arow * 4 + 0) * 2]), qq0 = aload_f(&attscal[(arow * 4 + 0) * 2 + 1]);
      float mq1 = aload_f(&attscal[(arow * 4 + 1) * 2]), qq1 = aload_f(&attscal[(arow * 4 + 1) * 2 + 1]);
      float mq2 = aload_f(&attscal[(arow * 4 + 2) * 2]), qq2 = aload_f(&attscal[(arow * 4 + 2) * 2 + 1]);
      float mq3 = aload_f(&attscal[(arow * 4 + 3) * 2]), qq3 = aload_f(&attscal[(arow * 4 + 3) * 2 + 1]);
      float mm = fmaxf(fmaxf(mq0, mq1), fmaxf(mq2, mq3));
      float w0 = __expf(mq0 - mm), w1 = __expf(mq1 - mm), w2 = __expf(mq2 - mm), w3 = __expf(mq3 - mm);
      float inv = 1.0f / (w0 * qq0 + w1 * qq1 + w2 * qq2 + w3 * qq3);
      w0 *= inv; w1 *= inv; w2 *= inv; w3 *= inv;
      const float* av0 = attvq + (long)(arow * 4 + 0) * 1024 + klane;
      const float* av1 = attvq + (long)(arow * 4 + 1) * 1024 + klane;
      const float* av2 = attvq + (long)(arow * 4 + 2) * 1024 + klane;
      const float* av3 = attvq + (long)(arow * 4 + 3) * 1024 + klane;
      f32x4 acc[4] = {{0,0,0,0},{0,0,0,0},{0,0,0,0},{0,0,0,0}};
      if (grp == 0) {
        int tok = dects[arow * NT + t];
        const float* er = emb + (long)tok * 256;
#pragma unroll
        for (int ks = 0; ks < 8; ++ks) {
          bf16x8 ah, al;
          if (tok) frag_f32(er + ks * 32 + klane, ah, al); else frag_zero(ah, al);
#pragma unroll
          for (int g = 0; g < 4; ++g) {
            const short* w = dW0ih + ((long)((cb >> 4) * 4 + g) * 40 + ks) * 1024 + lane * 8;
            bf16x8 wh = *(const bf16x8*)w, wl = *(const bf16x8*)(w + 512);
            acc[g] = mfma16(ah, wh, acc[g]);
            acc[g] = mfma16(al, wh, acc[g]);
            acc[g] = mfma16(ah, wl, acc[g]);
          }
        }
#pragma unroll 4
        for (int ks = 0; ks < 20; ++ks) {
          bf16x8 ah, al;
          frag_ctxq(av0 + ks * 32, av1 + ks * 32, av2 + ks * 32, av3 + ks * 32,
                    w0, w1, w2, w3, ah, al);
#pragma unroll
          for (int g = 0; g < 4; ++g) {
            const short* w = dW0ih + ((long)((cb >> 4) * 4 + g) * 40 + 8 + ks) * 1024 + lane * 8;
            bf16x8 wh = *(const bf16x8*)w, wl = *(const bf16x8*)(w + 512);
            acc[g] = mfma16(ah, wh, acc[g]);
            acc[g] = mfma16(al, wh, acc[g]);
            acc[g] = mfma16(ah, wl, acc[g]);
          }
        }
      } else {
        const int* h0r = d0h + (long)cur * BH + arow * NH + klane;
#pragma unroll 4
        for (int ks = 20; ks < 32; ++ks) {
          bf16x8 ah, al;
          frag_ctxq(av0 + ks * 32, av1 + ks * 32, av2 + ks * 32, av3 + ks * 32,
                    w0, w1, w2, w3, ah, al);
#pragma unroll
          for (int g = 0; g < 4; ++g) {
            const short* w = dW0ih + ((long)((cb >> 4) * 4 + g) * 40 + 8 + ks) * 1024 + lane * 8;
            bf16x8 wh = *(const bf16x8*)w, wl = *(const bf16x8*)(w + 512);
            acc[g] = mfma16(ah, wh, acc[g]);
            acc[g] = mfma16(al, wh, acc[g]);
            acc[g] = mfma16(ah, wl, acc[g]);
          }
        }
#pragma unroll 4
        for (int ks = 0; ks < 16; ++ks) {
          bf16x8 ah, al;
          frag_pka(h0r + ks * 32, ah, al);
#pragma unroll
          for (int g = 0; g < 4; ++g) {
            const short* w = dW0hh + ((long)((cb >> 4) * 4 + g) * 16 + ks) * 1024 + lane * 8;
            bf16x8 wh = *(const bf16x8*)w, wl = *(const bf16x8*)(w + 512);
            acc[g] = mfma16(ah, wh, acc[g]);
            acc[g] = mfma16(al, wh, acc[g]);
            acc[g] = mfma16(ah, wl, acc[g]);
          }
        }
#pragma unroll
        for (int g = 0; g < 4; ++g) sC[tw][g][lane] = acc[g];
      }
      __syncthreads();
      if (grp == 0) {
        int* hw = d0h + (long)nxt * BH;
#pragma unroll
        for (int g = 0; g < 4; ++g) acc[g] += sC[tw][g][lane];
#pragma unroll
        for (int r = 0; r < 4; ++r) {
          int row = r0 + ((lane >> 4) << 2) + r;
          float iv = sigm(acc[0][r] + db0[col]);
          float fv = sigm(acc[1][r] + db0[512 + col]);
          float gv = tanh_(acc[2][r] + db0[1024 + col]);
          float ov = sigm(acc[3][r] + db0[1536 + col]);
          float cv = fv * c0[r] + iv * gv; c0[r] = cv;
          astore_i(&hw[row * NH + col], pk(ov * tanh_(cv)));
        }
      }
    }
    gbar(bars, wg & 7, 64, 8, ++bc);
    // ---- P5: cell1; A: ih(h0 new); B: hh(h1 old); sC combine ----
    if (cw) {
      f32x4 acc[4] = {{0,0,0,0},{0,0,0,0},{0,0,0,0},{0,0,0,0}};
      if (grp == 0) {
        const int* h0n = d0h + (long)nxt * BH + arow * NH + klane;
#pragma unroll 4
        for (int ks = 0; ks < 16; ++ks) {
          bf16x8 ah, al;
          frag_pka(h0n + ks * 32, ah, al);
#pragma unroll
          for (int g = 0; g < 4; ++g) {
            const short* w = dW1ih + ((long)((cb >> 4) * 4 + g) * 16 + ks) * 1024 + lane * 8;
            bf16x8 wh = *(const bf16x8*)w, wl = *(const bf16x8*)(w + 512);
            acc[g] = mfma16(ah, wh, acc[g]);
            acc[g] = mfma16(al, wh, acc[g]);
            acc[g] = mfma16(ah, wl, acc[g]);
          }
        }
      } else {
        const int* h1c = d1h + (long)cur * BH + arow * NH + klane;
#pragma unroll 4
        for (int ks = 0; ks < 16; ++ks) {
          bf16x8 ah, al;
          frag_pka(h1c + ks * 32, ah, al);
#pragma unroll
          for (int g = 0; g < 4; ++g) {
            const short* w = dW1hh + ((long)((cb >> 4) * 4 + g) * 16 + ks) * 1024 + lane * 8;
            bf16x8 wh = *(const bf16x8*)w, wl = *(const bf16x8*)(w + 512);
            acc[g] = mfma16(ah, wh, acc[g]);
            acc[g] = mfma16(al, wh, acc[g]);
            acc[g] = mfma16(ah, wl, acc[g]);
          }
        }
#pragma unroll
        for (int g = 0; g < 4; ++g) sC[tw][g][lane] = acc[g];
      }
      __syncthreads();
      if (grp == 0) {
        int* hw = d1h + (long)nxt * BH;
#pragma unroll
        for (int g = 0; g < 4; ++g) acc[g] += sC[tw][g][lane];
#pragma unroll
        for (int r = 0; r < 4; ++r) {
          int row = r0 + ((lane >> 4) << 2) + r;
          float iv = sigm(acc[0][r] + db1[col]);
          float fv = sigm(acc[1][r] + db1[512 + col]);
          float gv = tanh_(acc[2][r] + db1[1024 + col]);
          float ov = sigm(acc[3][r] + db1[1536 + col]);
          float cv = fv * c1[r] + iv * gv; c1[r] = cv;
          float hv = ov * tanh_(cv);
          astore_i(&hw[row * NH + col], pk(hv));
          d1a[((long)t * NB + row) * 512 + col] = (f16)hv;
        }
      }
    }
    gbar(bars, wg & 7, 64, 8, ++bc);
  }
}

// logits [32768,512] = d1a(f16->bf16 pair) @ Wout^T(fp32->bf16 pair) + bout, to [B,T,V]
__global__ __launch_bounds__(256) void k_gemm_out(const f16* __restrict__ A,
    const float* __restrict__ Wout, const float* __restrict__ bias, float* __restrict__ out) {
  const int mt = blockIdx.x & 511, nt = blockIdx.x >> 9;
  const int wv = threadIdx.x >> 6, lane = threadIdx.x & 63;
  const int l15 = lane & 15, klane = (lane >> 4) * 8;
  const int r0 = mt * 64 + wv * 16, n0 = nt * 64;
  f32x4 acc[4] = {{0,0,0,0},{0,0,0,0},{0,0,0,0},{0,0,0,0}};
  const f16* ar = A + (long)(r0 + l15) * 512 + klane;
  for (int k = 0; k < 512; k += 32) {
    bf16x8 ah, al;
    frag_f16(ar + k, ah, al);
#pragma unroll
    for (int g = 0; g < 4; ++g) {
      bf16x8 wh, wl;
      frag_f32(Wout + (long)(n0 + g * 16 + l15) * 512 + k + klane, wh, wl);
      acc[g] = mfma16(ah, wh, acc[g]);
      acc[g] = mfma16(al, wh, acc[g]);
      acc[g] = mfma16(ah, wl, acc[g]);
    }
  }
#pragma unroll
  for (int g = 0; g < 4; ++g)
#pragma unroll
    for (int r = 0; r < 4; ++r) {
      int m = r0 + ((lane >> 4) << 2) + r;
      int tt = m >> 7, bb = m & 127;
      int n = n0 + g * 16 + l15;
      out[(long)bb * (NT * NV) + tt * NV + n] = acc[g][r] + bias[n];
    }
}

extern "C" void kernel_launch(void* const* d_in, const int* in_sizes, int n_in,
                              void* d_out, int out_size, void* d_ws, size_t ws_size,
                              hipStream_t stream) {
  char* basep = (char*)d_ws;
  size_t off = 0;
  auto alloc = [&](size_t bytes) -> void* {
    off = (off + 255) & ~(size_t)255;
    void* p = basep + off;
    off += bytes;
    return p;
  };
  int* bars = (int*)alloc(4096);
  float* hinit = (float*)alloc((size_t)4 * BH * 4);
  float* eb0 = (float*)alloc(4096 * 4);
  float* eb1 = (float*)alloc(4096 * 4);
  float* db0 = (float*)alloc(2048 * 4);
  float* db1 = (float*)alloc(2048 * 4);
  int* hbufE = (int*)alloc((size_t)4 * BH * 4);
  float* pbufE = (float*)alloc((size_t)4 * 128 * 2048 * 4);  // 4 MB gate partials
  // pool A (37.75 MB): encoder packed weights -> aprime (33.55 MB) after enc1
  char* pA = (char*)alloc((size_t)37748736);
  short* e0ihP = (short*)pA;
  short* e0hhP = (short*)(pA + 4194304);
  short* e1ihP = (short*)(pA + 12582912);
  short* e1hhP = (short*)(pA + 29360128);
  f16* aprime = (f16*)pA;
  // pool B (67.11 MB): y0 -> decoder packed weights + wq + d1a + dec state
  char* pB = (char*)alloc((size_t)67108864);
  f16* y0 = (f16*)pB;
  short* d0ihP = (short*)pB;                           // 10,485,760
  short* d0hhP = (short*)(pB + 10485760);              // 4,194,304
  short* d1ihP = (short*)(pB + 14680064);              // 4,194,304
  short* d1hhP = (short*)(pB + 18874368);              // 4,194,304
  int* wqPk = (int*)(pB + 23068672);                   // 2,097,152
  f16* d1a = (f16*)(pB + 25165824);                    // 33,554,432
  int* d0h = (int*)(pB + 58720256);                    // 524,288
  int* d1h = (int*)(pB + 59244544);                    // 524,288
  float* attvq = (float*)(pB + 59768832);              // 2,097,152
  float* attscal = (float*)(pB + 61865984);            // 4,096
  float* sbias = (float*)(pB + 61870080);              // 131,072
  if (off > ws_size) return;  // needs ~111 MB

  const int* source = (const int*)d_in[0];
  const int* dects = (const int*)d_in[1];
  const float* emb = (const float*)d_in[2];
  f16* eo = (f16*)d_out;  // 67 MB; dead before k_gemm_out overwrites with logits

  k_init<<<1024, 256, 0, stream>>>(hinit, bars);
  k_bias<<<16, 256, 0, stream>>>((const float*)d_in[5], (const float*)d_in[6],
                                 (const float*)d_in[9], (const float*)d_in[10],
                                 (const float*)d_in[13], (const float*)d_in[14],
                                 (const float*)d_in[17], (const float*)d_in[18],
                                 eb0, eb1, db0, db1);
  k_fragW<<<512, 256, 0, stream>>>((const float*)d_in[3], e0ihP, 256, 131072);
  k_fragW<<<1024, 256, 0, stream>>>((const float*)d_in[4], e0hhP, 512, 262144);
  k_fragW<<<2048, 256, 0, stream>>>((const float*)d_in[7], e1ihP, 1024, 524288);
  k_fragW<<<1024, 256, 0, stream>>>((const float*)d_in[8], e1hhP, 512, 262144);
  k_enc<0><<<512, 512, 0, stream>>>(source, emb, nullptr, e0ihP, e0hhP, eb0,
                                    hbufE, y0, hinit, pbufE, bars);
  k_enc<1><<<512, 512, 0, stream>>>(nullptr, nullptr, y0, e1ihP, e1hhP, eb1,
                                    hbufE, eo, hinit + 2 * BH, pbufE, bars + 256);
  // y0 dead: pack decoder weights into pool B
  k_fragW<<<1280, 256, 0, stream>>>((const float*)d_in[11], d0ihP, 1280, 327680);
  k_fragW<<<512, 256, 0, stream>>>((const float*)d_in[12], d0hhP, 512, 131072);
  k_fragW<<<512, 256, 0, stream>>>((const float*)d_in[15], d1ihP, 512, 131072);
  k_fragW<<<512, 256, 0, stream>>>((const float*)d_in[16], d1hhP, 512, 131072);
  k_convT<<<2048, 256, 0, stream>>>((const float*)d_in[19], wqPk);
  k_gemm_ap<<<4096, 256, 0, stream>>>(eo, wqPk, aprime);
  k_sbias<<<128, 256, 0, stream>>>(eo, (const float*)d_in[20], sbias);
  k_dec<<<512, 512, 0, stream>>>(dects, emb, source, aprime, sbias, eo,
                                 d0ihP, d0hhP, d1ihP, d1hhP, db0, db1, hinit,
                                 d0h, d1h, attscal, attvq, d1a, bars + 512);
  k_gemm_out<<<4096, 256, 0, stream>>>(d1a, (const float*)d_in[21],
                                       (const float*)d_in[22], (float*)d_out);
}

// Round 14
// 45842.911 us; speedup vs baseline: 1.2685x; 1.2685x over previous
//
#include <hip/hip_runtime.h>

typedef __attribute__((ext_vector_type(4))) float f32x4;
typedef __attribute__((ext_vector_type(8))) short bf16x8;
typedef __attribute__((ext_vector_type(4))) short bf16x4;
typedef __attribute__((ext_vector_type(4))) int i4v;
typedef _Float16 f16;
typedef __attribute__((ext_vector_type(8))) _Float16 f16x8;
typedef __attribute__((ext_vector_type(4))) _Float16 f16x4;

#define DEV static __device__ __forceinline__

constexpr int NB = 128;
constexpr int NS = 256;
constexpr int NT = 256;
constexpr int NV = 512;
constexpr int NH = 512;
constexpr int BH = NB * NH;  // 65536
constexpr float NEGV = -1e9f;

DEV float bf2f(short u) {
  unsigned int i = ((unsigned int)(unsigned short)u) << 16;
  float f; __builtin_memcpy(&f, &i, 4); return f;
}
DEV short f2bf(float x) {
  unsigned int i; __builtin_memcpy(&i, &x, 4);
  i += 0x7fffu + ((i >> 16) & 1u);
  return (short)(i >> 16);
}
DEV int pk(float x) {
  short h = f2bf(x);
  short l = f2bf(x - bf2f(h));
  return ((int)(unsigned short)h << 16) | (int)(unsigned short)l;
}
DEV float upkf(int v) { return bf2f((short)(v >> 16)) + bf2f((short)(v & 0xffff)); }
DEV float sigm(float x) { return 1.0f / (1.0f + __expf(-x)); }
DEV float tanh_(float x) { return 1.0f - 2.0f / (__expf(2.0f * x) + 1.0f); }
DEV f32x4 mfma16(bf16x8 a, bf16x8 b, f32x4 c) {
  return __builtin_amdgcn_mfma_f32_16x16x32_bf16(a, b, c, 0, 0, 0);
}

// ---- agent-scope (L3-coherent) atomics for intra-kernel cross-WG data ----
DEV int aload_i(const int* p) { return __hip_atomic_load(p, __ATOMIC_RELAXED, __HIP_MEMORY_SCOPE_AGENT); }
DEV void astore_i(int* p, int v) { __hip_atomic_store(p, v, __ATOMIC_RELAXED, __HIP_MEMORY_SCOPE_AGENT); }
DEV unsigned long long aload_l(const unsigned long long* p) {
  return __hip_atomic_load(p, __ATOMIC_RELAXED, __HIP_MEMORY_SCOPE_AGENT);
}
DEV float aload_f(const float* p) { return __hip_atomic_load(p, __ATOMIC_RELAXED, __HIP_MEMORY_SCOPE_AGENT); }
DEV void astore_f(float* p, float v) { __hip_atomic_store(p, v, __ATOMIC_RELAXED, __HIP_MEMORY_SCOPE_AGENT); }

// tree grid-barrier: 8 sub-counters (64B apart) + top counter; monotonic, no reset
DEV void gbar(int* bars, int sub, int subsz, int nsub, int bc) {
  asm volatile("s_waitcnt vmcnt(0) lgkmcnt(0)" ::: "memory");
  __syncthreads();
  if (threadIdx.x == 0) {
    int a = __hip_atomic_fetch_add(&bars[sub * 16], 1, __ATOMIC_RELAXED, __HIP_MEMORY_SCOPE_AGENT);
    if (a + 1 == subsz * bc)
      __hip_atomic_fetch_add(&bars[128], 1, __ATOMIC_RELAXED, __HIP_MEMORY_SCOPE_AGENT);
    while (aload_i(&bars[128]) < nsub * bc) __builtin_amdgcn_s_sleep(4);
    asm volatile("" ::: "memory");
  }
  __syncthreads();
}

// ---- fragment builders (all produce bf16 hi/lo pairs) ----
DEV void frag_zero(bf16x8& ah, bf16x8& al) { bf16x8 z{}; ah = z; al = z; }
DEV void frag_f32(const float* p, bf16x8& ah, bf16x8& al) {
  f32x4 a = *(const f32x4*)p, b = *(const f32x4*)(p + 4);
#pragma unroll
  for (int j = 0; j < 4; ++j) {
    short h0 = f2bf(a[j]); ah[j] = h0; al[j] = f2bf(a[j] - bf2f(h0));
    short h1 = f2bf(b[j]); ah[4 + j] = h1; al[4 + j] = f2bf(b[j] - bf2f(h1));
  }
}
DEV void frag_f16(const f16* p, bf16x8& ah, bf16x8& al) {
  f16x8 v = *(const f16x8*)p;
#pragma unroll
  for (int j = 0; j < 8; ++j) {
    float f = (float)v[j];
    short h = f2bf(f); ah[j] = h; al[j] = f2bf(f - bf2f(h));
  }
}
DEV void frag_pka(const int* p, bf16x8& ah, bf16x8& al) {  // packed via agent loads
#pragma unroll
  for (int jj = 0; jj < 4; ++jj) {
    unsigned long long u = aload_l((const unsigned long long*)p + jj);
    int va = (int)u, vb = (int)(u >> 32);
    ah[jj * 2] = (short)(va >> 16); al[jj * 2] = (short)(va & 0xffff);
    ah[jj * 2 + 1] = (short)(vb >> 16); al[jj * 2 + 1] = (short)(vb & 0xffff);
  }
}
DEV void frag_pk(const int* p, bf16x8& ah, bf16x8& al) {  // packed, plain loads
  i4v a = *(const i4v*)p; i4v b = *(const i4v*)(p + 4);
#pragma unroll
  for (int j = 0; j < 4; ++j) {
    ah[j] = (short)(a[j] >> 16); al[j] = (short)(a[j] & 0xffff);
    ah[4 + j] = (short)(b[j] >> 16); al[4 + j] = (short)(b[j] & 0xffff);
  }
}
// ctx merge of 2 fp32 s-half partials with 2 softmax scalars, then bf16-pair
DEV void frag_ctx2(const float* v0, const float* v1, float a0, float a1, bf16x8& ah, bf16x8& al) {
#pragma unroll
  for (int jj = 0; jj < 4; ++jj) {
    unsigned long long u0 = aload_l((const unsigned long long*)v0 + jj);
    unsigned long long u1 = aload_l((const unsigned long long*)v1 + jj);
    float f0a = __uint_as_float((unsigned)u0), f0b = __uint_as_float((unsigned)(u0 >> 32));
    float f1a = __uint_as_float((unsigned)u1), f1b = __uint_as_float((unsigned)(u1 >> 32));
    float ma = a0 * f0a + a1 * f1a, mb = a0 * f0b + a1 * f1b;
    short ha = f2bf(ma); ah[jj * 2] = ha; al[jj * 2] = f2bf(ma - bf2f(ha));
    short hb = f2bf(mb); ah[jj * 2 + 1] = hb; al[jj * 2 + 1] = f2bf(mb - bf2f(hb));
  }
}

// ---- prep kernels ----
__global__ void k_init(float* hinit, int* bars) {
  int i = blockIdx.x * 256 + threadIdx.x;
  if (i < 4 * BH) hinit[i] = 0.f;
  if (i < 768) bars[i] = 0;
}
__global__ void k_bias(const float* bi0, const float* bh0, const float* bi1, const float* bh1,
                       const float* dbi0, const float* dbh0, const float* dbi1, const float* dbh1,
                       float* e0, float* e1, float* d0, float* d1) {
  int i = blockIdx.x * 256 + threadIdx.x;
  if (i < 4096) { e0[i] = bi0[i] + bh0[i]; e1[i] = bi1[i] + bh1[i]; }
  if (i < 2048) { d0[i] = dbi0[i] + dbh0[i]; d1[i] = dbi1[i] + dbh1[i]; }
}
// fp32 W [nmat][2048][K] -> fragment layout [q=((mat*32+ct)*4+g)*KS+ks][hi 512 | lo 512 shorts]
__global__ void k_fragW(const float* __restrict__ src, short* __restrict__ dst,
                        int K, long tot) {
  long id = (long)blockIdx.x * 256 + threadIdx.x;
  if (id >= tot) return;
  int l = (int)(id & 63);
  long q = id >> 6;
  int KS = K >> 5;
  int ks = (int)(q % KS);
  long q2 = q / KS;
  int g = (int)(q2 & 3);
  long q3 = q2 >> 2;
  long mat = q3 >> 5;
  int ct = (int)(q3 & 31);
  const float* s = src + (mat * 2048 + g * 512 + ct * 16 + (l & 15)) * (long)K +
                   ks * 32 + (l >> 4) * 8;
  short* d = dst + q * 1024 + l * 8;
#pragma unroll
  for (int j = 0; j < 8; ++j) {
    float x = s[j];
    short h = f2bf(x);
    d[j] = h;
    d[512 + j] = f2bf(x - bf2f(h));
  }
}
// Wq [1024][512] fp32 -> [n 512][k 1024] packed bf16-pair ints (transposed)
__global__ void k_convT(const float* __restrict__ src, int* __restrict__ dst) {
  int i = blockIdx.x * 256 + threadIdx.x;  // 524288
  int n = i >> 10, k = i & 1023;
  dst[i] = pk(src[k * 512 + n]);
}

// ---- encoder layer, LDS-pinned weights (round-11 form, proven) ----
template <int LAYER>
__global__ __launch_bounds__(512, 2) void k_enc(
    const int* __restrict__ source, const float* __restrict__ emb,
    const f16* __restrict__ y0in,
    const short* __restrict__ WihP, const short* __restrict__ WhhP,
    const float* __restrict__ bsum,
    int* __restrict__ hbuf, f16* __restrict__ yout,
    float* __restrict__ hinitL, float* __restrict__ pbufE, int* bars) {
  constexpr int EX = LAYER ? 1024 : 256;
  constexpr int XK = EX / 32;
  constexpr int TOT = XK + 16;
  constexpr int HALF = TOT / 2;
  __shared__ short sW[HALF * 1024];
  const int wg = blockIdx.x, tid = threadIdx.x, wv = tid >> 6, lane = tid & 63;
  const int l15 = lane & 15, klane = (lane >> 4) * 8;
  const int xx = wg & 7, ii = wg >> 3;
  const int ct = xx * 4 + (ii & 3), g = (ii >> 2) & 3, dir = (ii >> 4) & 1, kp = (ii >> 5) & 1;
  const int cb = ct * 16;
  const short* wih = WihP + (long)dir * 4096 * EX;
  const short* whh = WhhP + (long)dir * 4096 * 512;
  const float* bs = bsum + dir * 2048;
  for (int i = tid; i < HALF * 128; i += 512) {
    int uu = i >> 7, off = (i & 127) * 8;
    int u = kp * HALF + uu;
    const short* src = (u < XK)
        ? wih + ((long)((ct * 4 + g) * XK + u) << 10) + off
        : whh + ((long)((ct * 4 + g) * 16 + (u - XK)) << 10) + off;
    *(bf16x8*)(sW + uu * 1024 + off) = *(const bf16x8*)src;
  }
  int bc = 0;
  {
    int i = wg * 512 + tid;
    int dp = i >> 16, rr = (i >> 9) & 127, c2 = i & 511;
    astore_i(&hbuf[dp * BH + rr * NH + c2], 0);
  }
  gbar(bars, xx, 64, 8, ++bc);
  const int arow = wv * 16 + l15;
  const int frow = g * 32 + (tid >> 4), fcol = cb + (tid & 15);
  float creg = 0.f;
  for (int t = 0; t < NS; ++t) {
    const int tt = dir ? (NS - 1 - t) : t;
    {
      f32x4 acc = {0.f, 0.f, 0.f, 0.f};
      int tok = 0;
      const float* er = nullptr;
      if (LAYER == 0 && kp == 0) { tok = source[arow * NS + tt]; er = emb + (long)tok * 256; }
      const f16* xr = LAYER ? (y0in + ((long)tt * NB + arow) * 1024 + klane) : nullptr;
      const int* hr = hbuf + (long)(dir * 2 + (t & 1)) * BH + arow * NH + klane;
#pragma unroll
      for (int uu = 0; uu < HALF; ++uu) {
        int u = kp * HALF + uu;
        bf16x8 ah, al;
        if (u < XK) {
          if (LAYER == 0) { if (tok) frag_f32(er + u * 32 + klane, ah, al); else frag_zero(ah, al); }
          else frag_f16(xr + u * 32, ah, al);
        } else {
          frag_pka(hr + (u - XK) * 32, ah, al);
        }
        const short* w = sW + uu * 1024 + lane * 8;
        bf16x8 wh = *(const bf16x8*)w, wl = *(const bf16x8*)(w + 512);
        acc = mfma16(ah, wh, acc);
        acc = mfma16(al, wh, acc);
        acc = mfma16(ah, wl, acc);
      }
#pragma unroll
      for (int r = 0; r < 4; ++r) {
        int row = wv * 16 + ((lane >> 4) << 2) + r;
        astore_f(&pbufE[(((long)(kp * 2 + dir) * 128 + row) << 11) + g * 512 + cb + l15], acc[r]);
      }
    }
    gbar(bars, xx, 64, 8, ++bc);
    if (kp == 0) {
      float g4[4];
#pragma unroll
      for (int gp = 0; gp < 4; ++gp)
        g4[gp] = aload_f(&pbufE[(((long)dir * 128 + frow) << 11) + gp * 512 + fcol]) +
                 aload_f(&pbufE[(((long)(2 + dir) * 128 + frow) << 11) + gp * 512 + fcol]) +
                 bs[gp * 512 + fcol];
      float iv = sigm(g4[0]), fv = sigm(g4[1]), gv = tanh_(g4[2]), ov = sigm(g4[3]);
      float cv = fv * creg + iv * gv; creg = cv;
      float hv = ov * tanh_(cv);
      astore_i(&hbuf[(long)(dir * 2 + ((t + 1) & 1)) * BH + frow * NH + fcol], pk(hv));
      if (LAYER == 0) yout[((long)tt * NB + frow) * 1024 + dir * 512 + fcol] = (f16)hv;
      else           yout[((long)frow * NS + tt) * 1024 + dir * 512 + fcol] = (f16)hv;
      if (t == NS - 1) {
        atomicAdd(&hinitL[frow * NH + fcol], hv);
        atomicAdd(&hinitL[BH + frow * NH + fcol], cv);
      }
    }
    gbar(bars, xx, 64, 8, ++bc);
  }
}

// aprime = eo @ Wq : M=32768 N=512 K=1024
__global__ __launch_bounds__(256) void k_gemm_ap(const f16* __restrict__ A,
    const int* __restrict__ WPk, f16* __restrict__ C) {
  const int mt = blockIdx.x & 511, nt = blockIdx.x >> 9;
  const int wv = threadIdx.x >> 6, lane = threadIdx.x & 63;
  const int l15 = lane & 15, klane = (lane >> 4) * 8;
  const int r0 = mt * 64 + wv * 16, n0 = nt * 64;
  f32x4 acc[4] = {{0,0,0,0},{0,0,0,0},{0,0,0,0},{0,0,0,0}};
  const f16* ar = A + (long)(r0 + l15) * 1024 + klane;
  for (int k = 0; k < 1024; k += 32) {
    bf16x8 ah, al;
    frag_f16(ar + k, ah, al);
#pragma unroll
    for (int g = 0; g < 4; ++g) {
      bf16x8 wh, wl;
      frag_pk(WPk + (long)(n0 + g * 16 + l15) * 1024 + k + klane, wh, wl);
      acc[g] = mfma16(ah, wh, acc[g]);
      acc[g] = mfma16(al, wh, acc[g]);
      acc[g] = mfma16(ah, wl, acc[g]);
    }
  }
#pragma unroll
  for (int g = 0; g < 4; ++g)
#pragma unroll
    for (int r = 0; r < 4; ++r) {
      int m = r0 + ((lane >> 4) << 2) + r;
      C[(long)m * 512 + n0 + g * 16 + l15] = (f16)acc[g][r];
    }
}

__global__ void k_sbias(const f16* __restrict__ eo, const float* __restrict__ bq,
                        float* __restrict__ sb) {
  int row = blockIdx.x * 256 + threadIdx.x;
  const f16* p = eo + (long)row * 1024;
  float acc = 0.f;
  for (int k = 0; k < 1024; k += 8) {
    f16x8 v = *(const f16x8*)(p + k);
#pragma unroll
    for (int j = 0; j < 8; ++j) acc += (float)v[j] * bq[k + j];
  }
  sb[row] = acc;
}

// persistent decoder (R11 geometry: 256 WGs x 512 thr, (512,2), 3 barriers/step).
// P2 ctx rewritten: 16B f16x8 loads, 4 s-subgroups x 128 dim-groups, LDS fp32 combine.
__global__ __launch_bounds__(512, 2) void k_dec(
    const int* __restrict__ dects, const float* __restrict__ emb,
    const int* __restrict__ source,
    const f16* __restrict__ aprime, const float* __restrict__ sbias,
    const f16* __restrict__ eo,
    const short* __restrict__ dW0ih, const short* __restrict__ dW0hh,
    const short* __restrict__ dW1ih, const short* __restrict__ dW1hh,
    const float* __restrict__ db0, const float* __restrict__ db1,
    const float* __restrict__ hinit,
    int* __restrict__ d0h, int* __restrict__ d1h,
    float* __restrict__ attscal, float* __restrict__ attv,
    f16* __restrict__ d1a, int* bars) {
  __shared__ float s_d1[512];
  __shared__ float s_scp[512];
  __shared__ float s_red[8];
  __shared__ float s_w[128];
  __shared__ float s_cx8[4][128][8];   // 16 KB ctx subgroup partials
  __shared__ f32x4 sC[4][4][64];       // 16 KB cell partial exchange
  const int wg = blockIdx.x, tid = threadIdx.x, wv = tid >> 6, lane = tid & 63;
  const int tw = wv & 3, grp = wv >> 2;
  const int l15 = lane & 15, klane = (lane >> 4) * 8;
  int bc = 0;
  if (tid < 256) {  // init parity-0 states from encoder-summed finals
    int idx = wg * 256 + tid;
    astore_i(&d0h[idx], pk(hinit[idx]));
    astore_i(&d1h[idx], pk(hinit[2 * BH + idx]));
  }
  const bool cw = (wg < 64);
  int r0 = 0, cb = 0;
  f32x4 c0 = {0,0,0,0}, c1 = {0,0,0,0};
  if (cw) {
    int xx = wg & 7, ii = wg >> 3;
    cb = (xx * 4 + (ii & 3)) * 16;
    r0 = (ii >> 2) * 64 + tw * 16;
    if (grp == 0) {
#pragma unroll
      for (int r = 0; r < 4; ++r) {
        int row = r0 + ((lane >> 4) << 2) + r;
        c0[r] = hinit[BH + row * NH + cb + l15];
        c1[r] = hinit[3 * BH + row * NH + cb + l15];
      }
    }
  }
  gbar(bars, wg & 7, 32, 8, ++bc);
  const int b = wg >> 1, sh = wg & 1;
  const int arow = r0 + l15, col = cb + l15;
  for (int t = 0; t < NT; ++t) {
    const int cur = t & 1, nxt = cur ^ 1;
    // ---- P2: attention ----
    {
      if (tid < 256) {
        unsigned long long u = aload_l((const unsigned long long*)(d1h + cur * BH + b * NH) + tid);
        s_d1[tid * 2] = upkf((int)u);
        s_d1[tid * 2 + 1] = upkf((int)(u >> 32));
      }
      __syncthreads();
      {  // scores: 4 K-quarters x 128 sl
        int kq = tid >> 7, sl = tid & 127;
        const f16* ap = aprime + (long)(b * NS + sh * 128 + sl) * 512 + kq * 128;
        const float* sd = s_d1 + kq * 128;
        float acc = 0.f;
#pragma unroll 4
        for (int k = 0; k < 128; k += 8) {
          f16x8 v = *(const f16x8*)(ap + k);
#pragma unroll
          for (int j = 0; j < 8; ++j) acc += (float)v[j] * sd[k + j];
        }
        s_scp[kq * 128 + sl] = acc;
      }
      __syncthreads();
      if (tid < 128) {
        int s = sh * 128 + tid;
        float sv = s_scp[tid] + s_scp[128 + tid] + s_scp[256 + tid] + s_scp[384 + tid];
        sv = (source[b * NS + s] != 0) ? (sv + sbias[b * NS + s]) : NEGV;
        s_scp[tid] = sv;
        float m = sv;
#pragma unroll
        for (int o = 32; o > 0; o >>= 1) m = fmaxf(m, __shfl_xor(m, o, 64));
        if (lane == 0) s_red[wv] = m;
      }
      __syncthreads();
      if (tid < 128) {
        float mc = fmaxf(s_red[0], s_red[1]);
        float pv = __expf(s_scp[tid] - mc);
        s_w[tid] = pv;
#pragma unroll
        for (int o = 32; o > 0; o >>= 1) pv += __shfl_xor(pv, o, 64);
        if (lane == 0) s_red[4 + wv] = pv;
      }
      __syncthreads();
      if (tid == 0) {
        astore_f(&attscal[(b * 2 + sh) * 2 + 0], fmaxf(s_red[0], s_red[1]));
        astore_f(&attscal[(b * 2 + sh) * 2 + 1], s_red[4] + s_red[5]);
      }
      {  // ctx: 4 s-subgroups of 32 rows x 128 dim-groups of 8; f16x8 16B loads
        int sub = tid >> 7, dg = tid & 127;
        float a[8] = {0,0,0,0,0,0,0,0};
        const f16* bp = eo + (long)(b * NS + sh * 128 + sub * 32) * 1024 + dg * 8;
        const float* wp = s_w + sub * 32;
#pragma unroll 4
        for (int sl = 0; sl < 32; ++sl) {
          float w = wp[sl];
          f16x8 v = *(const f16x8*)(bp + (long)sl * 1024);
#pragma unroll
          for (int j = 0; j < 8; ++j) a[j] += w * (float)v[j];
        }
#pragma unroll
        for (int j = 0; j < 8; ++j) s_cx8[sub][dg][j] = a[j];
      }
      __syncthreads();
      if (tid < 128) {  // combine 4 subgroups, one fp32 partial per s-half
        float* op = attv + (long)(b * 2 + sh) * 1024 + tid * 8;
#pragma unroll
        for (int j = 0; j < 8; ++j) {
          float s = s_cx8[0][tid][j] + s_cx8[1][tid][j] + s_cx8[2][tid][j] + s_cx8[3][tid][j];
          astore_f(op + j, s);
        }
      }
    }
    gbar(bars, wg & 7, 32, 8, ++bc);
    // ---- P4: cell0; A: emb(8)+ctx(0..19); B: ctx(20..31)+h(16); sC combine ----
    if (cw) {
      float m0 = aload_f(&attscal[(arow * 2 + 0) * 2 + 0]), q0 = aload_f(&attscal[(arow * 2 + 0) * 2 + 1]);
      float m1 = aload_f(&attscal[(arow * 2 + 1) * 2 + 0]), q1 = aload_f(&attscal[(arow * 2 + 1) * 2 + 1]);
      float mm = fmaxf(m0, m1);
      float e0 = __expf(m0 - mm), e1 = __expf(m1 - mm);
      float inv = 1.0f / (e0 * q0 + e1 * q1);
      float al0s = e0 * inv, al1s = e1 * inv;
      const float* av0 = attv + (long)(arow * 2 + 0) * 1024 + klane;
      const float* av1 = attv + (long)(arow * 2 + 1) * 1024 + klane;
      f32x4 acc[4] = {{0,0,0,0},{0,0,0,0},{0,0,0,0},{0,0,0,0}};
      if (grp == 0) {
        int tok = dects[arow * NT + t];
        const float* er = emb + (long)tok * 256;
#pragma unroll
        for (int ks = 0; ks < 8; ++ks) {
          bf16x8 ah, al;
          if (tok) frag_f32(er + ks * 32 + klane, ah, al); else frag_zero(ah, al);
#pragma unroll
          for (int g = 0; g < 4; ++g) {
            const short* w = dW0ih + ((long)((cb >> 4) * 4 + g) * 40 + ks) * 1024 + lane * 8;
            bf16x8 wh = *(const bf16x8*)w, wl = *(const bf16x8*)(w + 512);
            acc[g] = mfma16(ah, wh, acc[g]);
            acc[g] = mfma16(al, wh, acc[g]);
            acc[g] = mfma16(ah, wl, acc[g]);
          }
        }
#pragma unroll 4
        for (int ks = 0; ks < 20; ++ks) {
          bf16x8 ah, al;
          frag_ctx2(av0 + ks * 32, av1 + ks * 32, al0s, al1s, ah, al);
#pragma unroll
          for (int g = 0; g < 4; ++g) {
            const short* w = dW0ih + ((long)((cb >> 4) * 4 + g) * 40 + 8 + ks) * 1024 + lane * 8;
            bf16x8 wh = *(const bf16x8*)w, wl = *(const bf16x8*)(w + 512);
            acc[g] = mfma16(ah, wh, acc[g]);
            acc[g] = mfma16(al, wh, acc[g]);
            acc[g] = mfma16(ah, wl, acc[g]);
          }
        }
      } else {
        const int* h0r = d0h + (long)cur * BH + arow * NH + klane;
#pragma unroll 4
        for (int ks = 20; ks < 32; ++ks) {
          bf16x8 ah, al;
          frag_ctx2(av0 + ks * 32, av1 + ks * 32, al0s, al1s, ah, al);
#pragma unroll
          for (int g = 0; g < 4; ++g) {
            const short* w = dW0ih + ((long)((cb >> 4) * 4 + g) * 40 + 8 + ks) * 1024 + lane * 8;
            bf16x8 wh = *(const bf16x8*)w, wl = *(const bf16x8*)(w + 512);
            acc[g] = mfma16(ah, wh, acc[g]);
            acc[g] = mfma16(al, wh, acc[g]);
            acc[g] = mfma16(ah, wl, acc[g]);
          }
        }
#pragma unroll 4
        for (int ks = 0; ks < 16; ++ks) {
          bf16x8 ah, al;
          frag_pka(h0r + ks * 32, ah, al);
#pragma unroll
          for (int g = 0; g < 4; ++g) {
            const short* w = dW0hh + ((long)((cb >> 4) * 4 + g) * 16 + ks) * 1024 + lane * 8;
            bf16x8 wh = *(const bf16x8*)w, wl = *(const bf16x8*)(w + 512);
            acc[g] = mfma16(ah, wh, acc[g]);
            acc[g] = mfma16(al, wh, acc[g]);
            acc[g] = mfma16(ah, wl, acc[g]);
          }
        }
#pragma unroll
        for (int g = 0; g < 4; ++g) sC[tw][g][lane] = acc[g];
      }
      __syncthreads();
      if (grp == 0) {
        int* hw = d0h + (long)nxt * BH;
#pragma unroll
        for (int g = 0; g < 4; ++g) acc[g] += sC[tw][g][lane];
#pragma unroll
        for (int r = 0; r < 4; ++r) {
          int row = r0 + ((lane >> 4) << 2) + r;
          float iv = sigm(acc[0][r] + db0[col]);
          float fv = sigm(acc[1][r] + db0[512 + col]);
          float gv = tanh_(acc[2][r] + db0[1024 + col]);
          float ov = sigm(acc[3][r] + db0[1536 + col]);
          float cv = fv * c0[r] + iv * gv; c0[r] = cv;
          astore_i(&hw[row * NH + col], pk(ov * tanh_(cv)));
        }
      }
    }
    gbar(bars, wg & 7, 32, 8, ++bc);
    // ---- P5: cell1; A: ih(h0 new); B: hh(h1 old); sC combine ----
    if (cw) {
      f32x4 acc[4] = {{0,0,0,0},{0,0,0,0},{0,0,0,0},{0,0,0,0}};
      if (grp == 0) {
        const int* h0n = d0h + (long)nxt * BH + arow * NH + klane;
#pragma unroll 4
        for (int ks = 0; ks < 16; ++ks) {
          bf16x8 ah, al;
          frag_pka(h0n + ks * 32, ah, al);
#pragma unroll
          for (int g = 0; g < 4; ++g) {
            const short* w = dW1ih + ((long)((cb >> 4) * 4 + g) * 16 + ks) * 1024 + lane * 8;
            bf16x8 wh = *(const bf16x8*)w, wl = *(const bf16x8*)(w + 512);
            acc[g] = mfma16(ah, wh, acc[g]);
            acc[g] = mfma16(al, wh, acc[g]);
            acc[g] = mfma16(ah, wl, acc[g]);
          }
        }
      } else {
        const int* h1c = d1h + (long)cur * BH + arow * NH + klane;
#pragma unroll 4
        for (int ks = 0; ks < 16; ++ks) {
          bf16x8 ah, al;
          frag_pka(h1c + ks * 32, ah, al);
#pragma unroll
          for (int g = 0; g < 4; ++g) {
            const short* w = dW1hh + ((long)((cb >> 4) * 4 + g) * 16 + ks) * 1024 + lane * 8;
            bf16x8 wh = *(const bf16x8*)w, wl = *(const bf16x8*)(w + 512);
            acc[g] = mfma16(ah, wh, acc[g]);
            acc[g] = mfma16(al, wh, acc[g]);
            acc[g] = mfma16(ah, wl, acc[g]);
          }
        }
#pragma unroll
        for (int g = 0; g < 4; ++g) sC[tw][g][lane] = acc[g];
      }
      __syncthreads();
      if (grp == 0) {
        int* hw = d1h + (long)nxt * BH;
#pragma unroll
        for (int g = 0; g < 4; ++g) acc[g] += sC[tw][g][lane];
#pragma unroll
        for (int r = 0; r < 4; ++r) {
          int row = r0 + ((lane >> 4) << 2) + r;
          float iv = sigm(acc[0][r] + db1[col]);
          float fv = sigm(acc[1][r] + db1[512 + col]);
          float gv = tanh_(acc[2][r] + db1[1024 + col]);
          float ov = sigm(acc[3][r] + db1[1536 + col]);
          float cv = fv * c1[r] + iv * gv; c1[r] = cv;
          float hv = ov * tanh_(cv);
          astore_i(&hw[row * NH + col], pk(hv));
          d1a[((long)t * NB + row) * 512 + col] = (f16)hv;
        }
      }
    }
    gbar(bars, wg & 7, 32, 8, ++bc);
  }
}

// logits [32768,512] = d1a(f16->bf16 pair) @ Wout^T(fp32->bf16 pair) + bout, to [B,T,V]
__global__ __launch_bounds__(256) void k_gemm_out(const f16* __restrict__ A,
    const float* __restrict__ Wout, const float* __restrict__ bias, float* __restrict__ out) {
  const int mt = blockIdx.x & 511, nt = blockIdx.x >> 9;
  const int wv = threadIdx.x >> 6, lane = threadIdx.x & 63;
  const int l15 = lane & 15, klane = (lane >> 4) * 8;
  const int r0 = mt * 64 + wv * 16, n0 = nt * 64;
  f32x4 acc[4] = {{0,0,0,0},{0,0,0,0},{0,0,0,0},{0,0,0,0}};
  const f16* ar = A + (long)(r0 + l15) * 512 + klane;
  for (int k = 0; k < 512; k += 32) {
    bf16x8 ah, al;
    frag_f16(ar + k, ah, al);
#pragma unroll
    for (int g = 0; g < 4; ++g) {
      bf16x8 wh, wl;
      frag_f32(Wout + (long)(n0 + g * 16 + l15) * 512 + k + klane, wh, wl);
      acc[g] = mfma16(ah, wh, acc[g]);
      acc[g] = mfma16(al, wh, acc[g]);
      acc[g] = mfma16(ah, wl, acc[g]);
    }
  }
#pragma unroll
  for (int g = 0; g < 4; ++g)
#pragma unroll
    for (int r = 0; r < 4; ++r) {
      int m = r0 + ((lane >> 4) << 2) + r;
      int tt = m >> 7, bb = m & 127;
      int n = n0 + g * 16 + l15;
      out[(long)bb * (NT * NV) + tt * NV + n] = acc[g][r] + bias[n];
    }
}

extern "C" void kernel_launch(void* const* d_in, const int* in_sizes, int n_in,
                              void* d_out, int out_size, void* d_ws, size_t ws_size,
                              hipStream_t stream) {
  char* basep = (char*)d_ws;
  size_t off = 0;
  auto alloc = [&](size_t bytes) -> void* {
    off = (off + 255) & ~(size_t)255;
    void* p = basep + off;
    off += bytes;
    return p;
  };
  int* bars = (int*)alloc(4096);
  float* hinit = (float*)alloc((size_t)4 * BH * 4);
  float* eb0 = (float*)alloc(4096 * 4);
  float* eb1 = (float*)alloc(4096 * 4);
  float* db0 = (float*)alloc(2048 * 4);
  float* db1 = (float*)alloc(2048 * 4);
  int* hbufE = (int*)alloc((size_t)4 * BH * 4);
  float* pbufE = (float*)alloc((size_t)4 * 128 * 2048 * 4);  // 4 MB gate partials
  // pool A (37.75 MB): encoder packed weights -> aprime (33.55 MB) after enc1
  char* pA = (char*)alloc((size_t)37748736);
  short* e0ihP = (short*)pA;
  short* e0hhP = (short*)(pA + 4194304);
  short* e1ihP = (short*)(pA + 12582912);
  short* e1hhP = (short*)(pA + 29360128);
  f16* aprime = (f16*)pA;
  // pool B (67.11 MB): y0 -> decoder packed weights + wq + d1a + dec state
  char* pB = (char*)alloc((size_t)67108864);
  f16* y0 = (f16*)pB;
  short* d0ihP = (short*)pB;                           // 10,485,760
  short* d0hhP = (short*)(pB + 10485760);              // 4,194,304
  short* d1ihP = (short*)(pB + 14680064);              // 4,194,304
  short* d1hhP = (short*)(pB + 18874368);              // 4,194,304
  int* wqPk = (int*)(pB + 23068672);                   // 2,097,152
  f16* d1a = (f16*)(pB + 25165824);                    // 33,554,432
  int* d0h = (int*)(pB + 58720256);                    // 524,288
  int* d1h = (int*)(pB + 59244544);                    // 524,288
  float* attv = (float*)(pB + 59768832);               // 1,048,576
  float* attscal = (float*)(pB + 60817408);            // 4,096
  float* sbias = (float*)(pB + 60821504);              // 131,072
  if (off > ws_size) return;  // needs ~111 MB

  const int* source = (const int*)d_in[0];
  const int* dects = (const int*)d_in[1];
  const float* emb = (const float*)d_in[2];
  f16* eo = (f16*)d_out;  // 67 MB; dead before k_gemm_out overwrites with logits

  k_init<<<1024, 256, 0, stream>>>(hinit, bars);
  k_bias<<<16, 256, 0, stream>>>((const float*)d_in[5], (const float*)d_in[6],
                                 (const float*)d_in[9], (const float*)d_in[10],
                                 (const float*)d_in[13], (const float*)d_in[14],
                                 (const float*)d_in[17], (const float*)d_in[18],
                                 eb0, eb1, db0, db1);
  k_fragW<<<512, 256, 0, stream>>>((const float*)d_in[3], e0ihP, 256, 131072);
  k_fragW<<<1024, 256, 0, stream>>>((const float*)d_in[4], e0hhP, 512, 262144);
  k_fragW<<<2048, 256, 0, stream>>>((const float*)d_in[7], e1ihP, 1024, 524288);
  k_fragW<<<1024, 256, 0, stream>>>((const float*)d_in[8], e1hhP, 512, 262144);
  k_enc<0><<<512, 512, 0, stream>>>(source, emb, nullptr, e0ihP, e0hhP, eb0,
                                    hbufE, y0, hinit, pbufE, bars);
  k_enc<1><<<512, 512, 0, stream>>>(nullptr, nullptr, y0, e1ihP, e1hhP, eb1,
                                    hbufE, eo, hinit + 2 * BH, pbufE, bars + 256);
  // y0 dead: pack decoder weights into pool B
  k_fragW<<<1280, 256, 0, stream>>>((const float*)d_in[11], d0ihP, 1280, 327680);
  k_fragW<<<512, 256, 0, stream>>>((const float*)d_in[12], d0hhP, 512, 131072);
  k_fragW<<<512, 256, 0, stream>>>((const float*)d_in[15], d1ihP, 512, 131072);
  k_fragW<<<512, 256, 0, stream>>>((const float*)d_in[16], d1hhP, 512, 131072);
  k_convT<<<2048, 256, 0, stream>>>((const float*)d_in[19], wqPk);
  k_gemm_ap<<<4096, 256, 0, stream>>>(eo, wqPk, aprime);
  k_sbias<<<128, 256, 0, stream>>>(eo, (const float*)d_in[20], sbias);
  k_dec<<<256, 512, 0, stream>>>(dects, emb, source, aprime, sbias, eo,
                                 d0ihP, d0hhP, d1ihP, d1hhP, db0, db1, hinit,
                                 d0h, d1h, attscal, attv, d1a, bars + 512);
  k_gemm_out<<<4096, 256, 0, stream>>>(d1a, (const float*)d_in[21],
                                       (const float*)d_in[22], (float*)d_out);
}